// Round 5
// baseline (693.201 us; speedup 1.0000x reference)
//
#include <hip/hip_runtime.h>
#include <hip/hip_bf16.h>
#include <cstdint>
#include <cstddef>

#define TLEN 2048
#define NB 2
#define DMODEL 1024
#define NH 16
#define NDH 64

typedef unsigned short ushortT;
typedef short bf16x8 __attribute__((ext_vector_type(8)));
typedef float f32x16 __attribute__((ext_vector_type(16)));

__device__ __forceinline__ ushortT f2bf(float f) {
  union { float f; unsigned int u; } x{f};
  unsigned int r = x.u + 0x7fff + ((x.u >> 16) & 1);   // RNE
  return (ushortT)(r >> 16);
}
__device__ __forceinline__ unsigned int pk2(float lo, float hi) {
  return ((unsigned int)f2bf(hi) << 16) | (unsigned int)f2bf(lo);
}
__device__ __forceinline__ float bf2f(ushortT u) {
  union { unsigned int u; float f; } x;
  x.u = ((unsigned int)u) << 16;
  return x.f;
}

__device__ __forceinline__ void gld_lds16(const void* g, void* l) {
  __builtin_amdgcn_global_load_lds(
      (const __attribute__((address_space(1))) unsigned int*)g,
      (__attribute__((address_space(3))) unsigned int*)l, 16, 0, 0);
}

// ---------------------------------------------------------------------------
// converts
// ---------------------------------------------------------------------------

__global__ __launch_bounds__(256) void cvt_bf16(const float* __restrict__ in,
                                                ushortT* __restrict__ out, int n4) {
  int i = blockIdx.x * 256 + threadIdx.x;
  if (i < n4) {
    float4 v = reinterpret_cast<const float4*>(in)[i];
    ushort4 o;
    o.x = f2bf(v.x); o.y = f2bf(v.y); o.z = f2bf(v.z); o.w = f2bf(v.w);
    reinterpret_cast<ushort4*>(out)[i] = o;
  }
}

__global__ __launch_bounds__(256) void cvt_mask(const int* __restrict__ mask,
                                                float* __restrict__ mfl) {
  int j = blockIdx.x * 256 + threadIdx.x;
  if (j < TLEN) {
    mfl[j]        = mask[j * NB]     ? 0.f : 1.f;
    mfl[TLEN + j] = mask[j * NB + 1] ? 0.f : 1.f;
  }
}

// ---------------------------------------------------------------------------
// bf16 MFMA GEMM (unchanged from round 4)
// ---------------------------------------------------------------------------

template <typename Epi>
__global__ __launch_bounds__(256) void gemm_bf16(const ushortT* __restrict__ A,
                                                 const ushortT* __restrict__ B,
                                                 int K, Epi epi) {
  __shared__ ushortT Al[128 * 64];
  __shared__ ushortT Bl[128 * 64];
  const int tid = threadIdx.x;
  const int lane = tid & 63;
  const int wv = tid >> 6;
  const int wm = wv >> 1, wn = wv & 1;
  const int m0 = blockIdx.y * 128;
  const int n0 = blockIdx.x * 128;
  const int r32 = lane & 31;
  const int hh = lane >> 5;

  f32x16 acc[2][2];
#pragma unroll
  for (int i = 0; i < 2; ++i)
#pragma unroll
    for (int j = 0; j < 2; ++j)
#pragma unroll
      for (int e = 0; e < 16; ++e) acc[i][j][e] = 0.f;

  for (int k0 = 0; k0 < K; k0 += 64) {
#pragma unroll
    for (int it = 0; it < 4; ++it) {
      int idx = it * 256 + tid;          // 1024 chunks of 16B
      int r = idx >> 3, c = idx & 7;
      int gcol = k0 + ((c ^ (r & 7)) << 3);
      gld_lds16(A + (size_t)(m0 + r) * K + gcol, Al + idx * 8);
      gld_lds16(B + (size_t)(n0 + r) * K + gcol, Bl + idx * 8);
    }
    asm volatile("s_waitcnt vmcnt(0)");
    __syncthreads();
#pragma unroll
    for (int kc = 0; kc < 4; ++kc) {
      int lc = kc * 2 + hh;              // logical 16B chunk in row
      bf16x8 af[2], bfr[2];
#pragma unroll
      for (int f = 0; f < 2; ++f) {
        int ar = wm * 64 + f * 32 + r32;
        af[f] = *(const bf16x8*)(Al + ar * 64 + ((lc ^ (ar & 7)) << 3));
        int br = wn * 64 + f * 32 + r32;
        bfr[f] = *(const bf16x8*)(Bl + br * 64 + ((lc ^ (br & 7)) << 3));
      }
#pragma unroll
      for (int i = 0; i < 2; ++i)
#pragma unroll
        for (int j = 0; j < 2; ++j)
          acc[i][j] = __builtin_amdgcn_mfma_f32_32x32x16_bf16(af[i], bfr[j],
                                                              acc[i][j], 0, 0, 0);
    }
    __syncthreads();
  }

#pragma unroll
  for (int i = 0; i < 2; ++i)
#pragma unroll
    for (int j = 0; j < 2; ++j)
#pragma unroll
      for (int rg = 0; rg < 16; ++rg) {
        int m = m0 + wm * 64 + i * 32 + (rg & 3) + 8 * (rg >> 2) + 4 * hh;
        int n = n0 + wn * 64 + j * 32 + r32;
        epi.store(m, n, acc[i][j][rg]);
      }
}

struct EpiQKV {
  ushortT* qb; ushortT* kb; ushortT* vtb; const float* bias;
  __device__ void store(int m, int n, float val) const {
    int t = m >> 1, b = m & 1;
    int which = n >> 10;
    int h = (n >> 6) & (NH - 1);
    int dh = n & (NDH - 1);
    int bh = b * NH + h;
    if (which == 0)
      qb[((size_t)bh * TLEN + t) * NDH + dh] = f2bf(val + bias[(h << 6) | dh]);
    else if (which == 1)
      kb[((size_t)bh * TLEN + t) * NDH + dh] = f2bf(val);
    else
      vtb[((size_t)bh * NDH + dh) * TLEN + t] = f2bf(val);
  }
};

struct EpiRK {
  ushortT* rk;
  __device__ void store(int m, int n, float val) const {
    int h = n >> 6, dh = n & 63;
    rk[((size_t)h * TLEN + m) * NDH + dh] = f2bf(val);
  }
};

struct EpiOut {
  float* out;
  __device__ void store(int m, int n, float val) const {
    out[(size_t)m * DMODEL + n] = val;
  }
};

// ---------------------------------------------------------------------------
// MFMA attention, software-pipelined.
// Block = (bh, 128 q rows); 4 waves x 32 q rows. XCD-affine block swizzle:
// wg i -> XCD i%8 (round-robin); XCD c owns bh in [4c,4c+4) x 16 q-tiles,
// so each XCD's K/V/rk working set (3 MB) fits its private L2.
// rk/K loads for chunk t+1 prefetched into registers while computing t
// (two named buffers, static indexing); V/mask issued at top of compute.
// ---------------------------------------------------------------------------

struct KRK { bf16x8 rk0[4], rk1[4], kk[4]; };

__device__ __forceinline__ void ld_chunk(KRK& P, int j0, int q0, int ql, int hh,
                                         const ushortT* Rh, const ushortT* Kbh) {
  int jc = min(j0, TLEN - 32);
  const int w1b = 2016 - q0 + jc;
  const int w2b = jc - q0 - 33;
  int r0 = ((jc <= q0) ? w1b : w2b) + ql;
  int r1 = ((jc < q0) ? w1b : w2b) + 32 + ql;
  r0 = max(0, min(r0, TLEN - 1));
  r1 = max(0, min(r1, TLEN - 1));
  const ushortT* s0 = Rh + (size_t)r0 * NDH + hh * 8;
  const ushortT* s1 = Rh + (size_t)r1 * NDH + hh * 8;
  const ushortT* sk = Kbh + (size_t)(jc + ql) * NDH + hh * 8;
#pragma unroll
  for (int c = 0; c < 4; ++c) {
    P.rk0[c] = *(const bf16x8*)(s0 + c * 16);
    P.rk1[c] = *(const bf16x8*)(s1 + c * 16);
    P.kk[c]  = *(const bf16x8*)(sk + c * 16);
  }
}

__device__ __forceinline__ void compute_chunk(
    const KRK& P, int j0, int q0, int qg, int ql, int hh,
    const bf16x8* Qf, const bf16x8* Qs, float (*Wp)[32],
    const ushortT* Vbh, const float* mflb, ushortT* pbrow,
    f32x16& pacc0, f32x16& pacc1, float& l_acc) {
  const bool t0w1 = (j0 <= q0);
  const bool t1w1 = (j0 < q0);

  // early issue: V rows + mask for this chunk (consumed at the end)
  const ushortT* vrow0 = Vbh + (size_t)ql * TLEN + j0 + 8 * hh;
  const ushortT* vrow1 = Vbh + (size_t)(32 + ql) * TLEN + j0 + 8 * hh;
  bf16x8 v00 = *(const bf16x8*)(vrow0);
  bf16x8 v01 = *(const bf16x8*)(vrow0 + 16);
  bf16x8 v10 = *(const bf16x8*)(vrow1);
  bf16x8 v11 = *(const bf16x8*)(vrow1 + 16);
  float4 mf4[4];
#pragma unroll
  for (int g = 0; g < 4; ++g)
    mf4[g] = *(const float4*)(mflb + j0 + 8 * g + 4 * hh);

  f32x16 f0, f1, cacc;
#pragma unroll
  for (int i = 0; i < 16; ++i) { f0[i] = 0.f; f1[i] = 0.f; cacc[i] = 0.f; }

  __builtin_amdgcn_s_setprio(1);
#pragma unroll
  for (int c = 0; c < 4; ++c)
    f0 = __builtin_amdgcn_mfma_f32_32x32x16_bf16(P.rk0[c], t0w1 ? Qf[c] : Qs[c], f0, 0, 0, 0);
#pragma unroll
  for (int c = 0; c < 4; ++c)
    f1 = __builtin_amdgcn_mfma_f32_32x32x16_bf16(P.rk1[c], t1w1 ? Qf[c] : Qs[c], f1, 0, 0, 0);
#pragma unroll
  for (int c = 0; c < 4; ++c)
    cacc = __builtin_amdgcn_mfma_f32_32x32x16_bf16(P.kk[c], Qf[c], cacc, 0, 0, 0);
  __builtin_amdgcn_s_setprio(0);

#pragma unroll
  for (int r = 0; r < 16; ++r) {
    Wp[(r & 3) + 8 * (r >> 2) + 4 * hh][ql] = f0[r];
    Wp[32 + (r & 3) + 8 * (r >> 2) + 4 * hh][ql] = f1[r];
  }

  float p[16];
#pragma unroll
  for (int r = 0; r < 16; ++r) {
    int jrow = (r & 3) + 8 * (r >> 2) + 4 * hh;
    int jg = j0 + jrow;
    float bd = (jg == qg + 1) ? 0.f : Wp[jrow - ql + 31][ql];
    float sc = (cacc[r] + bd) * 0.125f;
    float mv = (&mf4[r >> 2].x)[r & 3];
    float pv = mv * __expf(sc);
    p[r] = pv;
    l_acc += pv;
  }

#pragma unroll
  for (int g = 0; g < 4; ++g) {
    uint2 st;
    st.x = pk2(p[4 * g + 0], p[4 * g + 1]);
    st.y = pk2(p[4 * g + 2], p[4 * g + 3]);
    *reinterpret_cast<uint2*>(pbrow + j0 + 8 * g + 4 * hh) = st;
  }

#pragma unroll
  for (int kh = 0; kh < 2; ++kh) {
    unsigned int u0 = pk2(p[8 * kh + 0], p[8 * kh + 1]);
    unsigned int u1 = pk2(p[8 * kh + 2], p[8 * kh + 3]);
    unsigned int u2 = pk2(p[8 * kh + 4], p[8 * kh + 5]);
    unsigned int u3 = pk2(p[8 * kh + 6], p[8 * kh + 7]);
    unsigned int t0 = (unsigned int)__shfl_xor((int)u0, 32);
    unsigned int t1 = (unsigned int)__shfl_xor((int)u1, 32);
    unsigned int t2 = (unsigned int)__shfl_xor((int)u2, 32);
    unsigned int t3 = (unsigned int)__shfl_xor((int)u3, 32);
    unsigned int fr[4];
    fr[0] = hh ? t2 : u0;
    fr[1] = hh ? t3 : u1;
    fr[2] = hh ? u2 : t0;
    fr[3] = hh ? u3 : t1;
    bf16x8 pa = *reinterpret_cast<bf16x8*>(fr);
    __builtin_amdgcn_s_setprio(1);
    pacc0 = __builtin_amdgcn_mfma_f32_32x32x16_bf16(pa, kh ? v01 : v00, pacc0, 0, 0, 0);
    pacc1 = __builtin_amdgcn_mfma_f32_32x32x16_bf16(pa, kh ? v11 : v10, pacc1, 0, 0, 0);
    __builtin_amdgcn_s_setprio(0);
  }
}

__global__ __launch_bounds__(256, 2) void attn_mfma(
    const ushortT* __restrict__ qb, const ushortT* __restrict__ kb,
    const ushortT* __restrict__ vtb, const ushortT* __restrict__ rkb,
    const float* __restrict__ mfl, float* __restrict__ prob,
    float* __restrict__ l_s, ushortT* __restrict__ av_bf) {
  __shared__ float W[4][64][32];

  // XCD-affine swizzle: wg -> XCD wg%8; XCD c gets bh 4c..4c+3, all q-tiles
  const int flat = blockIdx.x;
  const int xc = flat & 7;
  const int rr = flat >> 3;
  const int bh = 4 * xc + (rr & 3);
  const int qt = rr >> 2;

  const int b = bh >> 4, h = bh & 15;
  const int wv = threadIdx.x >> 6;
  const int lane = threadIdx.x & 63;
  const int ql = lane & 31;
  const int hh = lane >> 5;
  const int q0 = qt * 128 + wv * 32;
  const int qg = q0 + ql;

  const ushortT* Qbh = qb + (size_t)bh * TLEN * NDH;
  const ushortT* Kbh = kb + (size_t)bh * TLEN * NDH;
  const ushortT* Vbh = vtb + (size_t)bh * NDH * TLEN;
  const ushortT* Rh  = rkb + (size_t)h * TLEN * NDH;
  const float* mflb  = mfl + (size_t)b * TLEN;
  float (*Wp)[32] = W[wv];

  bf16x8 Qf[4], Qs[4];
  {
    int r2 = min(qg + 1, TLEN - 1);
#pragma unroll
    for (int c = 0; c < 4; ++c) {
      Qf[c] = *(const bf16x8*)(Qbh + (size_t)qg * NDH + c * 16 + hh * 8);
      Qs[c] = *(const bf16x8*)(Qbh + (size_t)r2 * NDH + c * 16 + hh * 8);
    }
  }

  f32x16 pacc0, pacc1;
#pragma unroll
  for (int i = 0; i < 16; ++i) { pacc0[i] = 0.f; pacc1[i] = 0.f; }
  float l_acc = 0.f;

  ushortT* pbrow = (ushortT*)prob + ((size_t)bh * TLEN + qg) * 4096 + 2048;

  KRK A, B;
  ld_chunk(A, 0, q0, ql, hh, Rh, Kbh);
  for (int j0 = 0; j0 < TLEN; j0 += 64) {
    ld_chunk(B, j0 + 32, q0, ql, hh, Rh, Kbh);
    compute_chunk(A, j0, q0, qg, ql, hh, Qf, Qs, Wp, Vbh, mflb, pbrow,
                  pacc0, pacc1, l_acc);
    ld_chunk(A, j0 + 64, q0, ql, hh, Rh, Kbh);
    compute_chunk(B, j0 + 32, q0, qg, ql, hh, Qf, Qs, Wp, Vbh, mflb, pbrow,
                  pacc0, pacc1, l_acc);
  }

  float lt = l_acc + __shfl_xor(l_acc, 32);
  if (lane < 32) l_s[(size_t)bh * TLEN + qg] = lt;
  float inv = 1.0f / lt;
#pragma unroll
  for (int r = 0; r < 16; ++r) {
    int qrow = (r & 3) + 8 * (r >> 2) + 4 * hh;
    float iv = __shfl(inv, qrow);
    size_t aoff = ((size_t)(q0 + qrow) * NB + b) * DMODEL + h * NDH;
    av_bf[aoff + ql] = f2bf(pacc0[r] * iv);
    av_bf[aoff + 32 + ql] = f2bf(pacc1[r] * iv);
  }
}

// ---------------------------------------------------------------------------
// prob row: read bf16 p~ from upper half of the row's 8KB slot, barrier,
// write f32 p~/l over the whole slot. Row-local overlap only.
// ---------------------------------------------------------------------------

__global__ __launch_bounds__(256) void rescale_kernel(float* __restrict__ prob,
                                                      const float* __restrict__ l_s) {
  const int row = blockIdx.x;
  const float inv = 1.0f / l_s[row];
  const int t = threadIdx.x;
  const ushortT* src = (const ushortT*)prob + (size_t)row * 4096 + 2048 + t * 8;
  uint4 u = *reinterpret_cast<const uint4*>(src);
  __syncthreads();
  float o[8];
  o[0] = bf2f((ushortT)(u.x & 0xffff)) * inv;
  o[1] = bf2f((ushortT)(u.x >> 16)) * inv;
  o[2] = bf2f((ushortT)(u.y & 0xffff)) * inv;
  o[3] = bf2f((ushortT)(u.y >> 16)) * inv;
  o[4] = bf2f((ushortT)(u.z & 0xffff)) * inv;
  o[5] = bf2f((ushortT)(u.z >> 16)) * inv;
  o[6] = bf2f((ushortT)(u.w & 0xffff)) * inv;
  o[7] = bf2f((ushortT)(u.w >> 16)) * inv;
  float4* dst = reinterpret_cast<float4*>(prob + (size_t)row * 2048 + t * 8);
  dst[0] = make_float4(o[0], o[1], o[2], o[3]);
  dst[1] = make_float4(o[4], o[5], o[6], o[7]);
}

// ---------------------------------------------------------------------------

extern "C" void kernel_launch(void* const* d_in, const int* in_sizes, int n_in,
                              void* d_out, int out_size, void* d_ws, size_t ws_size,
                              hipStream_t stream) {
  const float* w      = (const float*)d_in[0];   // (T,B,D)
  const float* r      = (const float*)d_in[1];   // (T,D)
  const float* w_qkv  = (const float*)d_in[2];   // (3072,1024)
  const float* w_r    = (const float*)d_in[3];   // (1024,1024)
  const float* w_o    = (const float*)d_in[4];   // (1024,1024)
  const float* bias   = (const float*)d_in[5];   // (16,64)
  const int* mask     = (const int*)d_in[6];     // (T,B) int32

  float* out  = (float*)d_out;
  float* prob = out + (size_t)TLEN * NB * DMODEL;

  const size_t SZ = (size_t)NB * NH * TLEN * NDH;        // 4194304
  ushortT* w_bf    = (ushortT*)d_ws;
  ushortT* wqkv_bf = w_bf + (size_t)4096 * 1024;
  ushortT* r_bf    = wqkv_bf + (size_t)3072 * 1024;
  ushortT* wr_bf   = r_bf + (size_t)2048 * 1024;
  ushortT* wo_bf   = wr_bf + (size_t)1024 * 1024;
  ushortT* q_bf    = wo_bf + (size_t)1024 * 1024;
  ushortT* k_bf    = q_bf + SZ;
  ushortT* vt_bf   = k_bf + SZ;
  ushortT* rk_bf   = vt_bf + SZ;
  ushortT* av_bf   = rk_bf + SZ / 2;
  float* l_s       = (float*)(av_bf + SZ);
  float* mfl       = l_s + (size_t)NB * NH * TLEN;

  cvt_bf16<<<4096, 256, 0, stream>>>(w, w_bf, 4096 * 1024 / 4);
  cvt_bf16<<<3072, 256, 0, stream>>>(w_qkv, wqkv_bf, 3072 * 1024 / 4);
  cvt_bf16<<<2048, 256, 0, stream>>>(r, r_bf, 2048 * 1024 / 4);
  cvt_bf16<<<1024, 256, 0, stream>>>(w_r, wr_bf, 1024 * 1024 / 4);
  cvt_bf16<<<1024, 256, 0, stream>>>(w_o, wo_bf, 1024 * 1024 / 4);
  cvt_mask<<<8, 256, 0, stream>>>(mask, mfl);

  EpiQKV e1{q_bf, k_bf, vt_bf, bias};
  gemm_bf16<EpiQKV><<<dim3(3072 / 128, 4096 / 128), 256, 0, stream>>>(w_bf, wqkv_bf, DMODEL, e1);
  EpiRK e2{rk_bf};
  gemm_bf16<EpiRK><<<dim3(1024 / 128, 2048 / 128), 256, 0, stream>>>(r_bf, wr_bf, DMODEL, e2);

  attn_mfma<<<dim3(512), 256, 0, stream>>>(q_bf, k_bf, vt_bf, rk_bf,
                                           mfl, prob, l_s, av_bf);
  rescale_kernel<<<dim3(NB * NH * TLEN), 256, 0, stream>>>(prob, l_s);

  EpiOut e5{out};
  gemm_bf16<EpiOut><<<dim3(1024 / 128, 4096 / 128), 256, 0, stream>>>(av_bf, wo_bf, DMODEL, e5);
}